// Round 1
// baseline (3302.503 us; speedup 1.0000x reference)
//
#include <hip/hip_runtime.h>
#include <hip/hip_bf16.h>
#include <math.h>

#define SEQ 512
#define NB  64
#define NIN 512
#define NH  1024
#define NO  512

typedef __bf16 bf16x8 __attribute__((ext_vector_type(8)));
typedef float  f32x4  __attribute__((ext_vector_type(4)));
typedef unsigned int u32x4 __attribute__((ext_vector_type(4)));

__device__ __forceinline__ f32x4 mfma16(bf16x8 a, bf16x8 b, f32x4 c) {
  return __builtin_amdgcn_mfma_f32_16x16x32_bf16(a, b, c, 0, 0, 0);
}

// Payload is pre-split (hi,lo) bf16 packed in one u32 per h element.
// unpack8: 8 consecutive packed elems (4x u64) -> hi-frag / lo-frag bf16x8.
__device__ __forceinline__ void unpack8(const unsigned long long* qp,
                                        bf16x8& ahi, bf16x8& alo) {
  u32x4 hw, lw;
#pragma unroll
  for (int u = 0; u < 4; ++u) {
    unsigned long long qq = qp[u];
    unsigned int w0 = (unsigned int)qq;
    unsigned int w1 = (unsigned int)(qq >> 32);
    hw[u] = (w0 & 0xffffu) | (w1 << 16);
    lw[u] = (w0 >> 16) | (w1 & 0xffff0000u);
  }
  ahi = __builtin_bit_cast(bf16x8, hw);
  alo = __builtin_bit_cast(bf16x8, lw);
}

#define SPIN_LIM 20000  // ~5ms+ of polling -> visible FAIL, never a hang

// Persistent RNN, slot-handshake exchange (replaces value-tag polling).
// Grid: 256 WGs = 4 groups (16 batch rows) x 64 WGs (16-col j-slice of H).
// 4 waves/WG = 4 K-quarters. Weights register-resident as bf16 hi/lo frags.
//
// Protocol per step t:
//   consume: poll 64 slots (4B sc1 load/lane) until all == t, then bulk-read
//            the packed h_t fragments ONCE (sc1, MALL-coherent).
//   publish: each wave finalizes rows r=wv (reduce via LDS, tanh, pack
//            hi/lo u32, sc1 store), then s_waitcnt vmcnt(0)  [release: acks
//            its h stores AND its h_{t-1} reads at the MALL] and stores
//            slot = t+1.
// Safety: slots stay == t until every WG consumed h_t (each WG bumps its own
// slot only after its poll succeeded), so exact-equality polls never miss and
// depth-2 parity reuse has no WAR hazard. Consumer data loads are issued only
// after observing the slot, so MALL service order guarantees they see the
// released data. Poison 0xAAAAAAAA and run-N leftovers (slot=512) never match
// a live target before being overwritten. t=0 reads h0 input directly.
__global__ __launch_bounds__(256, 1)
void rnn_slot(const float* __restrict__ x, const float* __restrict__ h0,
              const float* __restrict__ i_h, const float* __restrict__ h_h,
              const float* __restrict__ h_o, const float* __restrict__ b_i,
              const float* __restrict__ b_o, float* __restrict__ out,
              unsigned int* __restrict__ hbuf) {
  const int bid  = blockIdx.x;
  const int g    = bid & 3;          // group id (batch slice)
  const int w    = bid >> 2;         // 0..63  (hidden-column slice)
  const int wv   = threadIdx.x >> 6; // wave 0..3 = K-quarter
  const int lane = threadIdx.x & 63;
  const int tn   = lane & 15;        // MFMA A-row (batch) / C col
  const int tq   = lane >> 4;        // MFMA k-sub / C row-block
  const int Bg   = g * 16;
  const int Jw   = w * 16;
  const int Ow   = w * 8;
  const int kb0  = wv * 256;         // this wave's H-k base
  const int xb0  = wv * 128;         // this wave's IN-k base

  __shared__ float red_h[2][4][256]; // [parity][writer wave][r*64+lane]
  __shared__ float red_o[2][4][256];
  __shared__ int   sh_dead;
  if (threadIdx.x == 0) sh_dead = 0;

  // ---- invariant weight fragments in registers (bf16 hi/lo split) ----
  bf16x8 whi[8], wlo[8], hof[8], ihhi[4], ihlo[4];
#pragma unroll
  for (int c = 0; c < 8; ++c) {
    const int kb = kb0 + c * 32 + tq * 8;
#pragma unroll
    for (int j = 0; j < 8; ++j) {
      float v = h_h[(kb + j) * NH + Jw + tn];
      __bf16 hi = (__bf16)v;
      whi[c][j] = hi;
      wlo[c][j] = (__bf16)(v - (float)hi);
      float vo = (tn < 8) ? h_o[(kb + j) * NO + Ow + tn] : 0.0f;
      hof[c][j] = (__bf16)vo;
    }
  }
#pragma unroll
  for (int c = 0; c < 4; ++c) {
    const int kb = xb0 + c * 32 + tq * 8;
#pragma unroll
    for (int j = 0; j < 8; ++j) {
      float v = i_h[(kb + j) * NH + Jw + tn];
      __bf16 hi = (__bf16)v;
      ihhi[c][j] = hi;
      ihlo[c][j] = (__bf16)(v - (float)hi);
    }
  }
  const float bi = b_i[Jw + tn];
  const float bo = (tn < 8) ? b_o[Ow + tn] : 0.0f;

  unsigned int* pb = hbuf;                  // [2][64][1024] packed u32 = 512KB
  int* slots = (int*)(hbuf + 2 * 65536);    // [4 groups][64 WG][4 wv] = 4KB
  const int rowu   = (Bg + tn) * NH + kb0 + tq * 8; // lane A-frag base (u32)
  const int sread  = g * 256 + wv * 64 + lane;      // the 64 producers I need
  const int swrite = g * 256 + w * 4 + wv;          // my slot
  const int myrow  = Bg + tq * 4 + wv;              // row this wave finalizes

  __syncthreads();  // sh_dead visible

  for (int t = 0; t < SEQ; ++t) {
    f32x4 aH0 = {0.f, 0.f, 0.f, 0.f}, aH1 = {0.f, 0.f, 0.f, 0.f};
    f32x4 aO0 = {0.f, 0.f, 0.f, 0.f}, aO1 = {0.f, 0.f, 0.f, 0.f};

    // ---- xi = x @ i_h (independent of h_t; overlaps others' publish) ----
#pragma unroll
    for (int c = 0; c < 4; ++c) {
      const float* xp = x + (size_t)(t * NB + Bg + tn) * NIN + xb0 + c * 32 + tq * 8;
      f32x4 xa = *(const f32x4*)xp;
      f32x4 xb2 = *(const f32x4*)(xp + 4);
      bf16x8 xhi, xlo;
#pragma unroll
      for (int e = 0; e < 4; ++e) {
        __bf16 h1 = (__bf16)xa[e];
        xhi[e] = h1; xlo[e] = (__bf16)(xa[e] - (float)h1);
        __bf16 h2 = (__bf16)xb2[e];
        xhi[4 + e] = h2; xlo[4 + e] = (__bf16)(xb2[e] - (float)h2);
      }
      if (c & 1) {
        aH1 = mfma16(xhi, ihhi[c], aH1);
        aH1 = mfma16(xlo, ihhi[c], aH1);
        aH1 = mfma16(xhi, ihlo[c], aH1);
      } else {
        aH0 = mfma16(xhi, ihhi[c], aH0);
        aH0 = mfma16(xlo, ihhi[c], aH0);
        aH0 = mfma16(xhi, ihlo[c], aH0);
      }
    }

    if (t == 0) {
      // ---- h_0 straight from the input: no exchange, no poll ----
#pragma unroll
      for (int c = 0; c < 8; ++c) {
        const float* hp = h0 + (size_t)(Bg + tn) * NH + kb0 + c * 32 + tq * 8;
        f32x4 ha = *(const f32x4*)hp;
        f32x4 hb2 = *(const f32x4*)(hp + 4);
        bf16x8 ahi, alo;
#pragma unroll
        for (int e = 0; e < 4; ++e) {
          __bf16 h1 = (__bf16)ha[e];
          ahi[e] = h1; alo[e] = (__bf16)(ha[e] - (float)h1);
          __bf16 h2 = (__bf16)hb2[e];
          ahi[4 + e] = h2; alo[4 + e] = (__bf16)(hb2[e] - (float)h2);
        }
        if (c & 1) {
          aH1 = mfma16(ahi, whi[c], aH1);
          aH1 = mfma16(alo, whi[c], aH1);
          aH1 = mfma16(ahi, wlo[c], aH1);
          aO1 = mfma16(ahi, hof[c], aO1);
          aO1 = mfma16(alo, hof[c], aO1);
        } else {
          aH0 = mfma16(ahi, whi[c], aH0);
          aH0 = mfma16(alo, whi[c], aH0);
          aH0 = mfma16(ahi, wlo[c], aH0);
          aO0 = mfma16(ahi, hof[c], aO0);
          aO0 = mfma16(alo, hof[c], aO0);
        }
      }
    } else {
      // ---- slot poll: 1x 4B sc1 load per lane per round ----
      {
        int iter = 0;
        while (true) {
          int sv = __hip_atomic_load(&slots[sread], __ATOMIC_RELAXED,
                                     __HIP_MEMORY_SCOPE_AGENT);
          if (__all(sv == t)) break;
          if (++iter > SPIN_LIM) { sh_dead = 1; break; }
        }
      }
      asm volatile("" ::: "memory");  // keep data loads below the poll

      // ---- bulk-read packed h_t fragments ONCE ----
      const unsigned int* pbP = pb + (t & 1) * 65536 + rowu;
      unsigned long long q[32];
#pragma unroll
      for (int c = 0; c < 8; ++c) {
        const unsigned long long* p = (const unsigned long long*)(pbP + c * 32);
#pragma unroll
        for (int u = 0; u < 4; ++u)
          q[4 * c + u] = __hip_atomic_load(p + u, __ATOMIC_RELAXED,
                                           __HIP_MEMORY_SCOPE_AGENT);
      }
#pragma unroll
      for (int c = 0; c < 8; ++c) {
        bf16x8 ahi, alo;
        unpack8(&q[4 * c], ahi, alo);
        if (c & 1) {
          aH1 = mfma16(ahi, whi[c], aH1);
          aH1 = mfma16(alo, whi[c], aH1);
          aH1 = mfma16(ahi, wlo[c], aH1);
          aO1 = mfma16(ahi, hof[c], aO1);
          aO1 = mfma16(alo, hof[c], aO1);
        } else {
          aH0 = mfma16(ahi, whi[c], aH0);
          aH0 = mfma16(alo, whi[c], aH0);
          aH0 = mfma16(ahi, wlo[c], aH0);
          aO0 = mfma16(ahi, hof[c], aO0);
          aO0 = mfma16(alo, hof[c], aO0);
        }
      }
    }

    aH0 += aH1;
    aO0 += aO1;

    // ---- cross-wave K reduction, distributed: wave wv finalizes r=wv ----
    const int par = t & 1;
#pragma unroll
    for (int r = 0; r < 4; ++r)
      if (r != wv) {
        red_h[par][wv][r * 64 + lane] = aH0[r];
        red_o[par][wv][r * 64 + lane] = aO0[r];
      }
    __syncthreads();
    if (sh_dead) break;  // WG-uniform bail -> fast visible FAIL, no hang

    float hs = aH0[wv];
    float os = aO0[wv];
#pragma unroll
    for (int s = 0; s < 4; ++s)
      if (s != wv) {
        hs += red_h[par][s][wv * 64 + lane];
        os += red_o[par][s][wv * 64 + lane];
      }

    // tanh, pre-split hi/lo pack, publish h_{t+1}
    float v = tanhf(hs + bi);
    __bf16 vh = (__bf16)v;
    __bf16 vl = (__bf16)(v - (float)vh);
    unsigned int pk = (unsigned int)__builtin_bit_cast(unsigned short, vh)
                    | ((unsigned int)__builtin_bit_cast(unsigned short, vl) << 16);
    __hip_atomic_store(&pb[((t + 1) & 1) * 65536 + myrow * NH + Jw + tn], pk,
                       __ATOMIC_RELAXED, __HIP_MEMORY_SCOPE_AGENT);

    // o_{t-1} finish (VALU, runs while publish store is in flight)
    float o = os + bo;
    o = (o >= 0.f) ? o : 0.01f * o;

    // release: publish stores (and our h_{t-1} reads) acked at MALL, then slot
    asm volatile("s_waitcnt vmcnt(0)" ::: "memory");
    if (lane == 0)
      __hip_atomic_store(&slots[swrite], t + 1, __ATOMIC_RELAXED,
                         __HIP_MEMORY_SCOPE_AGENT);

    // off critical path: outputs
    if (t >= 1 && tn < 8)
      out[((size_t)(t - 1) * NB + myrow) * NO + Ow + tn] = o;
    if (t == SEQ - 1)
      out[(size_t)SEQ * NB * NO + (size_t)myrow * NH + Jw + tn] = v;
  }

  // ---- epilogue: o_{SEQ-1} from h_SEQ (parity 0, slot target SEQ) ----
  if (!sh_dead) {
    {
      int iter = 0;
      while (true) {
        int sv = __hip_atomic_load(&slots[sread], __ATOMIC_RELAXED,
                                   __HIP_MEMORY_SCOPE_AGENT);
        if (__all(sv == SEQ)) break;
        if (++iter > SPIN_LIM) break;
      }
    }
    asm volatile("" ::: "memory");
    const unsigned int* pbP = pb + (SEQ & 1) * 65536 + rowu;
    unsigned long long q[32];
#pragma unroll
    for (int c = 0; c < 8; ++c) {
      const unsigned long long* p = (const unsigned long long*)(pbP + c * 32);
#pragma unroll
      for (int u = 0; u < 4; ++u)
        q[4 * c + u] = __hip_atomic_load(p + u, __ATOMIC_RELAXED,
                                         __HIP_MEMORY_SCOPE_AGENT);
    }
    f32x4 aO0 = {0.f, 0.f, 0.f, 0.f}, aO1 = {0.f, 0.f, 0.f, 0.f};
#pragma unroll
    for (int c = 0; c < 8; ++c) {
      bf16x8 ahi, alo;
      unpack8(&q[4 * c], ahi, alo);
      if (c & 1) {
        aO1 = mfma16(ahi, hof[c], aO1);
        aO1 = mfma16(alo, hof[c], aO1);
      } else {
        aO0 = mfma16(ahi, hof[c], aO0);
        aO0 = mfma16(alo, hof[c], aO0);
      }
    }
    aO0 += aO1;
#pragma unroll
    for (int r = 0; r < 4; ++r)
      if (r != wv) red_o[0][wv][r * 64 + lane] = aO0[r];
    __syncthreads();
    float os = aO0[wv];
#pragma unroll
    for (int s = 0; s < 4; ++s)
      if (s != wv) os += red_o[0][s][wv * 64 + lane];
    if (tn < 8) {
      float o = os + bo;
      o = (o >= 0.f) ? o : 0.01f * o;
      out[((size_t)(SEQ - 1) * NB + myrow) * NO + Ow + tn] = o;
    }
  }
}

extern "C" void kernel_launch(void* const* d_in, const int* in_sizes, int n_in,
                              void* d_out, int out_size, void* d_ws, size_t ws_size,
                              hipStream_t stream) {
  (void)in_sizes; (void)n_in; (void)out_size; (void)ws_size;
  const float* x   = (const float*)d_in[0];
  const float* h0  = (const float*)d_in[1];
  const float* i_h = (const float*)d_in[2];
  const float* h_h = (const float*)d_in[3];
  const float* h_o = (const float*)d_in[4];
  const float* b_i = (const float*)d_in[5];
  const float* b_o = (const float*)d_in[6];
  float* out = (float*)d_out;
  unsigned int* hbuf = (unsigned int*)d_ws;  // 512KB packed h + 4KB slots.
                                             // 0xAA poison / stale-run slot
                                             // values never match a live
                                             // target -> no memset needed.

  void* args[] = {&x, &h0, &i_h, &h_h, &h_o, &b_i, &b_o, &out, &hbuf};
  hipError_t err = hipLaunchCooperativeKernel((const void*)rnn_slot,
                                              dim3(256), dim3(256), args, 0, stream);
  if (err != hipSuccess) {
    // Plain launch fallback: grid 256 <= 1 block/CU capacity -> co-resident.
    rnn_slot<<<dim3(256), dim3(256), 0, stream>>>(
        x, h0, i_h, h_h, h_o, b_i, b_o, out, hbuf);
  }
}

// Round 5
// 2812.568 us; speedup vs baseline: 1.1742x; 1.1742x over previous
//
#include <hip/hip_runtime.h>
#include <hip/hip_bf16.h>
#include <math.h>

#define SEQ 512
#define NB  64
#define NIN 512
#define NH  1024
#define NO  512

#define SPIN_LIM 20000  // bounded waits -> visible FAIL, never a watchdog hang

typedef __bf16 bf16x8 __attribute__((ext_vector_type(8)));
typedef float  f32x4  __attribute__((ext_vector_type(4)));
typedef unsigned int u32x4 __attribute__((ext_vector_type(4)));

__device__ __forceinline__ f32x4 mfma16(bf16x8 a, bf16x8 b, f32x4 c) {
  return __builtin_amdgcn_mfma_f32_16x16x32_bf16(a, b, c, 0, 0, 0);
}

// ---- exchange: agent-scope tag-in-data (the R0-session-PROVEN protocol) ----
// Board word = hi bf16 [31:16] | lo bf16 top-13 [15:3] | tag [2:0].
// tag(h_s) = (s+2)&7. Single-u32 store+load atomicity => the poll IS the data
// read: no producer ack, no flags, no fences anywhere on the critical path.
// Publisher stores via __hip_atomic relaxed AGENT (MALL-coherent, proven in
// R0/R1). Consumer polls with volatile 16B loads (re-issued every iteration;
// per-4B-word atomicity is what the tag check relies on -- tearing across
// words self-rejects per word). Poison 0xAA (tag 2) rejects at first uses
// (t=1 expects 3, t=2 expects 4); cross-run leftovers (tags 1/2 on parity
// 1/0) reject at t=1/2; depth-2 parity reuse is WAR-safe because a WG only
// reaches step t after ALL producers published h_t, i.e. every WG finished
// reading h_{t-1} (reads complete into registers before its publish of h_t).
#define TAG_READ(PARITY, TEXP)                                                 \
  {                                                                            \
    const volatile u32x4* rp = (const volatile u32x4*)(                        \
        board + (PARITY) * 8192 + (tn & 7) * 1024 + kb0 + tq * 8);             \
    const unsigned int Texp = (unsigned int)(TEXP);                            \
    int iter = 0;                                                              \
    while (true) {                                                             \
      _Pragma("unroll")                                                        \
      for (int c = 0; c < 8; ++c) {                                            \
        q[2 * c]     = rp[c * 8];                                              \
        q[2 * c + 1] = rp[c * 8 + 1];                                          \
      }                                                                        \
      unsigned int bad = 0;                                                    \
      _Pragma("unroll")                                                        \
      for (int i = 0; i < 16; ++i) {                                           \
        u32x4 vq = q[i];                                                       \
        bad |= (vq[0] ^ Texp) | (vq[1] ^ Texp) | (vq[2] ^ Texp) | (vq[3] ^ Texp); \
      }                                                                        \
      if (__all((bad & 7u) == 0)) break;                                       \
      if (++iter > SPIN_LIM) { sh_dead = 1; break; }                           \
    }                                                                          \
  }

// Persistent RNN, 8 teams x 32 WGs (team = bid&7: placement-INDEPENDENT for
// correctness; under default round-robin dispatch it is also XCD-local, which
// is a pure perf hint). Team g: batch rows [8g,8g+8). WG slot r = bid>>3:
// h-cols [32r,32r+32), o-cols [16r,16r+16). Waves = K-quarters; weights
// register-resident as bf16 hi/lo (AGPR-backed on the unified gfx950 file).
// A-rows 8..15 mirror rows 0..7 (only 8 batch rows/team); duplicate C rows
// are discarded by the tq<2 reduction guard.
// ws layout (u32 idx): 8 team boards [2 parity][8 rows][1024] = 512KB total.
// No slots, no claims, no memset needed.
__global__ __launch_bounds__(256, 1)
void rnn_team(const float* __restrict__ x, const float* __restrict__ h0,
              const float* __restrict__ i_h, const float* __restrict__ h_h,
              const float* __restrict__ h_o, const float* __restrict__ b_i,
              const float* __restrict__ b_o, float* __restrict__ out,
              unsigned int* __restrict__ ws) {
  const int bid = blockIdx.x;
  const int g   = bid & 7;           // team (batch slice; XCD under round-robin)
  const int r   = bid >> 3;          // 0..31 (hidden-column slice)
  const int wv  = threadIdx.x >> 6, lane = threadIdx.x & 63;
  const int tn  = lane & 15, tq = lane >> 4;

  __shared__ int sh_dead;
  __shared__ float red_h[2][4][256];  // [parity][wave][row*32 + col32]
  __shared__ float red_o[2][4][128];  // [parity][wave][row*16 + col16]
  if (threadIdx.x == 0) sh_dead = 0;

  const int Jw  = r * 32;    // h-col slice
  const int Ow  = r * 16;    // o-col slice
  const int kb0 = wv * 256;  // H K-quarter base
  const int xq0 = wv * 128;  // IN K-quarter base
  const int Bg  = g * 8;     // batch rows [Bg, Bg+8)
  unsigned int* board = ws + g * 16384;

  // ---- register-resident weights (bf16 hi/lo) ----
  bf16x8 whh_h[8][2], whh_l[8][2], who[8], wih_h[4][2], wih_l[4][2];
#pragma unroll
  for (int c = 0; c < 8; ++c) {
    const int kb = kb0 + c * 32 + tq * 8;
#pragma unroll
    for (int nf = 0; nf < 2; ++nf)
#pragma unroll
      for (int j = 0; j < 8; ++j) {
        float v = h_h[(kb + j) * NH + Jw + nf * 16 + tn];
        __bf16 hi = (__bf16)v;
        whh_h[c][nf][j] = hi;
        whh_l[c][nf][j] = (__bf16)(v - (float)hi);
      }
#pragma unroll
    for (int j = 0; j < 8; ++j)
      who[c][j] = (__bf16)h_o[(kb + j) * NO + Ow + tn];
  }
#pragma unroll
  for (int c = 0; c < 4; ++c) {
    const int kb = xq0 + c * 32 + tq * 8;
#pragma unroll
    for (int nf = 0; nf < 2; ++nf)
#pragma unroll
      for (int j = 0; j < 8; ++j) {
        float v = i_h[(kb + j) * NH + Jw + nf * 16 + tn];
        __bf16 hi = (__bf16)v;
        wih_h[c][nf][j] = hi;
        wih_l[c][nf][j] = (__bf16)(v - (float)hi);
      }
  }

  // publisher roles: h: all 64 lanes -> (row=2wv+(lane>>5), col32=lane&31);
  // o: lanes<32 -> (row=2wv+((lane>>4)&1), col16=lane&15)
  const int prow = 2 * wv + (lane >> 5);
  const int pcol = lane & 31;
  const int orow = 2 * wv + ((lane >> 4) & 1);
  const int ocol = lane & 15;
  const float bi_p = b_i[Jw + pcol];
  const float bo_p = b_o[Ow + ocol];

  __syncthreads();  // sh_dead visible

  // x prefetch (one step ahead), mirrored rows (tn&7)
  f32x4 xn[8];
#pragma unroll
  for (int c = 0; c < 4; ++c) {
    const float* xp = x + (size_t)(Bg + (tn & 7)) * NIN + xq0 + c * 32 + tq * 8;
    xn[2 * c]     = *(const f32x4*)xp;
    xn[2 * c + 1] = *(const f32x4*)(xp + 4);
  }

  for (int t = 0; t < SEQ; ++t) {
    f32x4 aH0 = {0.f, 0.f, 0.f, 0.f}, aH1 = {0.f, 0.f, 0.f, 0.f};
    f32x4 aO0 = {0.f, 0.f, 0.f, 0.f}, aO1 = {0.f, 0.f, 0.f, 0.f};

    // ---- xi = x_t @ W_ih from prefetched registers ----
#pragma unroll
    for (int c = 0; c < 4; ++c) {
      bf16x8 xhi, xlo;
#pragma unroll
      for (int e = 0; e < 4; ++e) {
        float f0 = xn[2 * c][e], f1 = xn[2 * c + 1][e];
        __bf16 h1 = (__bf16)f0; xhi[e] = h1; xlo[e] = (__bf16)(f0 - (float)h1);
        __bf16 h2 = (__bf16)f1; xhi[4 + e] = h2; xlo[4 + e] = (__bf16)(f1 - (float)h2);
      }
      aH0 = mfma16(xhi, wih_h[c][0], aH0);
      aH0 = mfma16(xlo, wih_h[c][0], aH0);
      aH0 = mfma16(xhi, wih_l[c][0], aH0);
      aH1 = mfma16(xhi, wih_h[c][1], aH1);
      aH1 = mfma16(xlo, wih_h[c][1], aH1);
      aH1 = mfma16(xhi, wih_l[c][1], aH1);
    }

    // ---- acquire h_t: tag-in-data poll (h0 direct from input at t=0) ----
    u32x4 q[16];
    if (t == 0) {
#pragma unroll
      for (int c = 0; c < 8; ++c) {
        const float* hp =
            h0 + (size_t)(Bg + (tn & 7)) * NH + kb0 + c * 32 + tq * 8;
        f32x4 ha = *(const f32x4*)hp;
        f32x4 hb = *(const f32x4*)(hp + 4);
#pragma unroll
        for (int u = 0; u < 4; ++u) {
          float f0 = ha[u];
          __bf16 hi0 = (__bf16)f0;
          unsigned int hw0 = (unsigned int)__builtin_bit_cast(unsigned short, hi0);
          unsigned int lw0 = (unsigned int)__builtin_bit_cast(
              unsigned short, (__bf16)(f0 - (float)hi0));
          q[2 * c][u] = (hw0 << 16) | (lw0 & 0xFFF8u);
          float f1 = hb[u];
          __bf16 hi1 = (__bf16)f1;
          unsigned int hw1 = (unsigned int)__builtin_bit_cast(unsigned short, hi1);
          unsigned int lw1 = (unsigned int)__builtin_bit_cast(
              unsigned short, (__bf16)(f1 - (float)hi1));
          q[2 * c + 1][u] = (hw1 << 16) | (lw1 & 0xFFF8u);
        }
      }
    } else {
      TAG_READ(t & 1, (t + 2) & 7);
    }

    // issue next-step x loads: latency hides under unpack+MFMA+reduce
    if (t + 1 < SEQ) {
#pragma unroll
      for (int c = 0; c < 4; ++c) {
        const float* xp = x + (size_t)((t + 1) * NB + Bg + (tn & 7)) * NIN +
                          xq0 + c * 32 + tq * 8;
        xn[2 * c]     = *(const f32x4*)xp;
        xn[2 * c + 1] = *(const f32x4*)(xp + 4);
      }
    }

    // ---- unpack (hi|lo planes) + MFMA ----
#pragma unroll
    for (int c = 0; c < 8; ++c) {
      u32x4 a = q[2 * c], b = q[2 * c + 1];
      u32x4 hw, lw;
      hw[0] = (a[0] >> 16) | (a[1] & 0xFFFF0000u);
      hw[1] = (a[2] >> 16) | (a[3] & 0xFFFF0000u);
      hw[2] = (b[0] >> 16) | (b[1] & 0xFFFF0000u);
      hw[3] = (b[2] >> 16) | (b[3] & 0xFFFF0000u);
      lw[0] = ((a[0] & 0xFFFFu) | (a[1] << 16)) & 0xFFF8FFF8u;
      lw[1] = ((a[2] & 0xFFFFu) | (a[3] << 16)) & 0xFFF8FFF8u;
      lw[2] = ((b[0] & 0xFFFFu) | (b[1] << 16)) & 0xFFF8FFF8u;
      lw[3] = ((b[2] & 0xFFFFu) | (b[3] << 16)) & 0xFFF8FFF8u;
      bf16x8 ahi = __builtin_bit_cast(bf16x8, hw);
      bf16x8 alo = __builtin_bit_cast(bf16x8, lw);
      aH0 = mfma16(ahi, whh_h[c][0], aH0);
      aH0 = mfma16(alo, whh_h[c][0], aH0);
      aH0 = mfma16(ahi, whh_l[c][0], aH0);
      aH1 = mfma16(ahi, whh_h[c][1], aH1);
      aH1 = mfma16(alo, whh_h[c][1], aH1);
      aH1 = mfma16(ahi, whh_l[c][1], aH1);
      if (c & 1) {
        aO1 = mfma16(ahi, who[c], aO1);
        aO1 = mfma16(alo, who[c], aO1);
      } else {
        aO0 = mfma16(ahi, who[c], aO0);
        aO0 = mfma16(alo, who[c], aO0);
      }
    }
    f32x4 aO = aO0 + aO1;

    // ---- cross-wave K reduction (depth-2 LDS); rows 8..15 are mirrors ----
    const int par = t & 1;
    if (tq < 2) {
#pragma unroll
      for (int rr = 0; rr < 4; ++rr) {
        red_h[par][wv][(tq * 4 + rr) * 32 + tn]      = aH0[rr];
        red_h[par][wv][(tq * 4 + rr) * 32 + 16 + tn] = aH1[rr];
        red_o[par][wv][(tq * 4 + rr) * 16 + tn]      = aO[rr];
      }
    }
    __syncthreads();
    if (sh_dead) break;  // WG-uniform bail -> visible FAIL, no hang

    // ---- publish h_{t+1}: tanh -> pack(hi|lo|tag) -> agent atomic store ----
    float hs = 0.f;
#pragma unroll
    for (int s = 0; s < 4; ++s) hs += red_h[par][s][prow * 32 + pcol];
    float v = tanhf(hs + bi_p);
    __bf16 vh = (__bf16)v;
    unsigned int hb16 = (unsigned int)__builtin_bit_cast(unsigned short, vh);
    unsigned int lb16 = (unsigned int)__builtin_bit_cast(
        unsigned short, (__bf16)(v - (float)vh));
    unsigned int pk = (hb16 << 16) | (lb16 & 0xFFF8u) | ((t + 3u) & 7u);
    __hip_atomic_store(&board[((t + 1) & 1) * 8192 + prow * 1024 + Jw + pcol],
                       pk, __ATOMIC_RELAXED, __HIP_MEMORY_SCOPE_AGENT);

    // ---- off critical path: o_{t-1} and h_final ----
    if (lane < 32) {
      float os = 0.f;
#pragma unroll
      for (int s = 0; s < 4; ++s) os += red_o[par][s][orow * 16 + ocol];
      float o = os + bo_p;
      o = (o >= 0.f) ? o : 0.01f * o;
      if (t >= 1)
        out[((size_t)(t - 1) * NB + Bg + orow) * NO + Ow + ocol] = o;
    }
    if (t == SEQ - 1)
      out[(size_t)SEQ * NB * NO + (size_t)(Bg + prow) * NH + Jw + pcol] = v;
  }

  // ---- epilogue: o_{SEQ-1} from h_SEQ (parity 0, tag (SEQ+2)&7 = 2) ----
  if (!sh_dead) {
    u32x4 q[16];
    TAG_READ(0, (SEQ + 2) & 7);
    f32x4 aO0 = {0.f, 0.f, 0.f, 0.f}, aO1 = {0.f, 0.f, 0.f, 0.f};
#pragma unroll
    for (int c = 0; c < 8; ++c) {
      u32x4 a = q[2 * c], b = q[2 * c + 1];
      u32x4 hw, lw;
      hw[0] = (a[0] >> 16) | (a[1] & 0xFFFF0000u);
      hw[1] = (a[2] >> 16) | (a[3] & 0xFFFF0000u);
      hw[2] = (b[0] >> 16) | (b[1] & 0xFFFF0000u);
      hw[3] = (b[2] >> 16) | (b[3] & 0xFFFF0000u);
      lw[0] = ((a[0] & 0xFFFFu) | (a[1] << 16)) & 0xFFF8FFF8u;
      lw[1] = ((a[2] & 0xFFFFu) | (a[3] << 16)) & 0xFFF8FFF8u;
      lw[2] = ((b[0] & 0xFFFFu) | (b[1] << 16)) & 0xFFF8FFF8u;
      lw[3] = ((b[2] & 0xFFFFu) | (b[3] << 16)) & 0xFFF8FFF8u;
      bf16x8 ahi = __builtin_bit_cast(bf16x8, hw);
      bf16x8 alo = __builtin_bit_cast(bf16x8, lw);
      if (c & 1) {
        aO1 = mfma16(ahi, who[c], aO1);
        aO1 = mfma16(alo, who[c], aO1);
      } else {
        aO0 = mfma16(ahi, who[c], aO0);
        aO0 = mfma16(alo, who[c], aO0);
      }
    }
    f32x4 aO = aO0 + aO1;
    if (tq < 2) {
#pragma unroll
      for (int rr = 0; rr < 4; ++rr)
        red_o[0][wv][(tq * 4 + rr) * 16 + tn] = aO[rr];
    }
    __syncthreads();
    if (lane < 32 && !sh_dead) {
      float os = 0.f;
#pragma unroll
      for (int s = 0; s < 4; ++s) os += red_o[0][s][orow * 16 + ocol];
      float o = os + bo_p;
      o = (o >= 0.f) ? o : 0.01f * o;
      out[((size_t)(SEQ - 1) * NB + Bg + orow) * NO + Ow + ocol] = o;
    }
  }
}

extern "C" void kernel_launch(void* const* d_in, const int* in_sizes, int n_in,
                              void* d_out, int out_size, void* d_ws, size_t ws_size,
                              hipStream_t stream) {
  (void)in_sizes; (void)n_in; (void)out_size; (void)ws_size;
  const float* x   = (const float*)d_in[0];
  const float* h0  = (const float*)d_in[1];
  const float* i_h = (const float*)d_in[2];
  const float* h_h = (const float*)d_in[3];
  const float* h_o = (const float*)d_in[4];
  const float* b_i = (const float*)d_in[5];
  const float* b_o = (const float*)d_in[6];
  float* out = (float*)d_out;
  unsigned int* ws = (unsigned int*)d_ws;  // 512KB boards; 0xAA poison and
                                           // cross-run leftovers self-reject
                                           // via tags -> no memset needed.

  void* args[] = {&x, &h0, &i_h, &h_h, &h_o, &b_i, &b_o, &out, &ws};
  hipError_t err = hipLaunchCooperativeKernel((const void*)rnn_team,
                                              dim3(256), dim3(256), args, 0, stream);
  if (err != hipSuccess) {
    // Plain launch fallback: grid 256 <= capacity -> co-resident in practice;
    // bounded spins make any violation a visible FAIL, not a hang.
    rnn_team<<<dim3(256), dim3(256), 0, stream>>>(
        x, h0, i_h, h_h, h_o, b_i, b_o, out, ws);
  }
}